// Round 2
// 8404.404 us; speedup vs baseline: 1.2255x; 1.2255x over previous
//
#include <hip/hip_runtime.h>

#define B_ 64
#define T_ 1024
#define I_ 512
#define H_ 1024
#define O_ 512
#define BH (B_*H_)   // 65536

using short8 = __attribute__((ext_vector_type(8))) short;
using f32x4  = __attribute__((ext_vector_type(4))) float;

__device__ __forceinline__ unsigned short f2b(float f) {
  unsigned int u = __float_as_uint(f);
  u = (u + 0x7fffu + ((u >> 16) & 1u)) >> 16;
  return (unsigned short)u;
}
__device__ __forceinline__ float b2f(unsigned short h) {
  return __uint_as_float(((unsigned int)h) << 16);
}

// wait only vmcnt==0 (gfx9 encoding: expcnt=7, lgkmcnt=0xF -> no wait on those)
#define WAIT_VM0() __builtin_amdgcn_s_waitcnt(0x0F70)

// async global->LDS, 16B per lane. LDS dest: wave-uniform base + lane*16 (linear).
__device__ __forceinline__ void glds16(const ushort* g, ushort* l) {
  __builtin_amdgcn_global_load_lds(
      (const __attribute__((address_space(1))) void*)g,
      (__attribute__((address_space(3))) void*)l, 16, 0, 0);
}

// ---------- cast kernels ----------
__global__ void cast4_kernel(const float* __restrict__ src, ushort* __restrict__ dst, int n4) {
  int i = blockIdx.x * 256 + threadIdx.x;
  if (i >= n4) return;
  float4 v = ((const float4*)src)[i];
  ushort4 o; o.x = f2b(v.x); o.y = f2b(v.y); o.z = f2b(v.z); o.w = f2b(v.w);
  ((ushort4*)dst)[i] = o;
}

// extract W_gate[:, H:2H] -> bf16 [H][H] row-major
__global__ void cast_gate_kernel(const float* __restrict__ src, ushort* __restrict__ dst) {
  int i = blockIdx.x * 256 + threadIdx.x;   // over H*H/4 = 262144
  int row = i >> 8, k4 = (i & 255) << 2;
  float4 v = *(const float4*)(src + (size_t)row * 2048 + 1024 + k4);
  ushort4 o; o.x = f2b(v.x); o.y = f2b(v.y); o.z = f2b(v.z); o.w = f2b(v.w);
  ((ushort4*)dst)[((size_t)row << 8) + (k4 >> 2)] = o;
}

// inputs fp32 [B][T][I] -> bf16 Abf[(t*64+b)][I]  (row layout matching z/a/h)
__global__ __launch_bounds__(256)
void cast_inputs_kernel(const float* __restrict__ src, ushort* __restrict__ dst) {
  int i = blockIdx.x * 256 + threadIdx.x;        // over B*T*I/4 = 8388608
  int rp = i >> 7;                               // b*T + t  (128 float4 per 512-row)
  int e4 = (i & 127) << 2;
  int b = rp >> 10, t = rp & 1023;
  float4 v = *(const float4*)(src + ((size_t)rp << 9) + e4);
  ushort4 o; o.x = f2b(v.x); o.y = f2b(v.y); o.z = f2b(v.z); o.w = f2b(v.w);
  *(ushort4*)(dst + (((size_t)(t << 6) + b) << 9) + e4) = o;
}

// ---------- m97-structure tiled GEMM: C[M,N] = A[M,K] @ W[N,K]^T + bias ----------
// 128x128 tile, BK=32, 256 threads (4 waves, 2x2 quadrants of 64x64),
// global_load_lds(16B) staging, single LDS buffer, 2 barriers per K-step.
// modeC: 0 -> bf16 row-major [M][N]; 1 -> fp32 out[b][t][n] with b=row&63, t=row>>6.
__global__ __launch_bounds__(256)
void gemm_bt_tiled(const ushort* __restrict__ A, const ushort* __restrict__ W,
                   const float* __restrict__ bias, void* __restrict__ Cout,
                   int M, int N, int K, int modeC)
{
  __shared__ __align__(16) ushort As[128 * 32];
  __shared__ __align__(16) ushort Bs[128 * 32];

  const int tid  = threadIdx.x;
  const int wave = tid >> 6, lane = tid & 63;
  const int q = lane >> 4, col = lane & 15;

  const int n0 = blockIdx.x * 128;
  const int m0 = blockIdx.y * 128;

  const int wr = (wave >> 1) * 64;   // wave's row quadrant in tile
  const int wc = (wave & 1) * 64;    // wave's col quadrant

  // staging map: thread i stages 16B -> LDS bytes [i*16, i*16+16) = row i>>2, ksub (i&3)*8
  const int srow = tid >> 2;
  const int skk  = (tid & 3) << 3;
  const ushort* Ag = A + (size_t)(m0 + srow) * K + skk;
  const ushort* Wg = W + (size_t)(n0 + srow) * K + skk;
  ushort* AsW = As + wave * 512;     // per-wave LDS base (1 KB per wave per issue)
  ushort* BsW = Bs + wave * 512;

  f32x4 acc[4][4];
  #pragma unroll
  for (int i = 0; i < 4; ++i)
    #pragma unroll
    for (int j = 0; j < 4; ++j) acc[i][j] = (f32x4){0.f, 0.f, 0.f, 0.f};

  const ushort* Asr = As + ((size_t)(wr + col) << 5) + q * 8;
  const ushort* Bsr = Bs + ((size_t)(wc + col) << 5) + q * 8;

  for (int k0 = 0; k0 < K; k0 += 32) {
    __syncthreads();                               // all waves done reading LDS
    glds16(Ag + k0,                   AsW);        // rows m0+ 0..63
    glds16(Ag + (size_t)64 * K + k0,  AsW + 2048); // rows m0+64..127
    glds16(Wg + k0,                   BsW);
    glds16(Wg + (size_t)64 * K + k0,  BsW + 2048);
    __syncthreads();                               // drains vmcnt -> LDS ready

    short8 af[4], bf[4];
    #pragma unroll
    for (int mt = 0; mt < 4; ++mt) af[mt] = *(const short8*)(Asr + mt * 16 * 32);
    #pragma unroll
    for (int nt = 0; nt < 4; ++nt) bf[nt] = *(const short8*)(Bsr + nt * 16 * 32);
    #pragma unroll
    for (int mt = 0; mt < 4; ++mt)
      #pragma unroll
      for (int nt = 0; nt < 4; ++nt)
        acc[mt][nt] = __builtin_amdgcn_mfma_f32_16x16x32_bf16(af[mt], bf[nt], acc[mt][nt], 0, 0, 0);
  }

  #pragma unroll
  for (int nt = 0; nt < 4; ++nt) {
    int n = n0 + wc + nt * 16 + col;
    float bv = bias[n];
    #pragma unroll
    for (int mt = 0; mt < 4; ++mt) {
      #pragma unroll
      for (int r = 0; r < 4; ++r) {
        int row = m0 + wr + mt * 16 + q * 4 + r;
        float v = acc[mt][nt][r] + bv;
        if (modeC == 0) {
          ((ushort*)Cout)[(size_t)row * N + n] = f2b(v);
        } else {
          int b = row & 63, t = row >> 6;
          ((float*)Cout)[(size_t)b * (T_ * O_) + (size_t)t * O_ + n] = v;
        }
      }
    }
  }
}

// ---------- scan (unchanged from verified version) ----------
// 4 groups x 16 batches. 128 WGs x 64 threads: member = blockIdx&63 owns cols
// [16m,16m+16); pair p = blockIdx>>6 owns groups {2p, 2p+1}, interleaved to
// hide publish/poll latency. Sync = relaxed agent atomics only.
__device__ __forceinline__ void scan_step(
    int t, int g, int b0, int n0, int lane, int q, int col,
    const short8* __restrict__ wfv, ushort* __restrict__ hbuf,
    float* __restrict__ hfinal, int* __restrict__ flags,
    const float zv[4], const float av[4], float hp[4])
{
  const int fidx = (g << 6) + lane;
  for (;;) {
    int v = __hip_atomic_load(&flags[fidx], __ATOMIC_RELAXED, __HIP_MEMORY_SCOPE_AGENT);
    if (__ballot(v < t) == 0ull) break;
    __builtin_amdgcn_s_sleep(1);
  }
  __builtin_amdgcn_fence(__ATOMIC_ACQUIRE, "workgroup");  // compiler barrier only

  const ushort* hrow = hbuf + (size_t)(t - 1) * BH + (size_t)(b0 + col) * H_ + q * 8;
  f32x4 acc0 = {0.f, 0.f, 0.f, 0.f}, acc1 = {0.f, 0.f, 0.f, 0.f};
  #pragma unroll
  for (int ks = 0; ks < 32; ks += 2) {
    short8 h0f = *(const short8*)(hrow + ks * 32);
    short8 h1f = *(const short8*)(hrow + (ks + 1) * 32);
    acc0 = __builtin_amdgcn_mfma_f32_16x16x32_bf16(h0f, wfv[ks * 64 + lane], acc0, 0, 0, 0);
    acc1 = __builtin_amdgcn_mfma_f32_16x16x32_bf16(h1f, wfv[(ks + 1) * 64 + lane], acc1, 0, 0, 0);
  }
  f32x4 S = acc0 + acc1;

  #pragma unroll
  for (int r = 0; r < 4; ++r) {
    int b = b0 + q * 4 + r;
    float x  = S[r] + av[r];
    float u  = 1.0f / (1.0f + __expf(-x));
    float hn = u * hp[r] + (1.0f - u) * zv[r];
    hp[r] = hn;
    unsigned int own = f2b(hn);
    unsigned int other = ((unsigned int)__shfl_xor((int)own, 1, 64)) & 0xffffu;
    if ((col & 1) == 0) {
      unsigned int dw = own | (other << 16);
      __hip_atomic_store((unsigned int*)(hbuf + (size_t)t * BH + (size_t)b * H_ + n0 + col),
                         dw, __ATOMIC_RELAXED, __HIP_MEMORY_SCOPE_AGENT);
    }
    if (t == T_) hfinal[(size_t)b * H_ + n0 + col] = hn;
  }
  WAIT_VM0();
  if (lane == 0)
    __hip_atomic_store(&flags[(g << 6) + (n0 >> 4)], t + 1,
                       __ATOMIC_RELAXED, __HIP_MEMORY_SCOPE_AGENT);
}

__global__ __launch_bounds__(64)
void scan_kernel(const ushort* __restrict__ z, const ushort* __restrict__ a,
                 ushort* __restrict__ hbuf, const float* __restrict__ Wgate,
                 const float* __restrict__ h0, float* __restrict__ hfinal,
                 int* __restrict__ flags)
{
  __shared__ __align__(16) short Wf[32 * 64 * 8];  // 32KB: [ks][lane][8]

  const int tid = threadIdx.x;
  const int member = blockIdx.x & 63;
  const int pairid = blockIdx.x >> 6;          // 0 or 1
  const int gA = pairid * 2, gB = pairid * 2 + 1;
  const int b0A = gA << 4, b0B = gB << 4;
  const int n0 = member << 4;
  const int lane = tid;
  const int q = lane >> 4, col = lane & 15;

  short8* wfv = (short8*)Wf;

  {
    const float* wsrc = Wgate + (size_t)(n0 + col) * 2048 + (q * 8);
    for (int ks = 0; ks < 32; ++ks) {
      float4 w0 = *(const float4*)(wsrc + ks * 32);
      float4 w1 = *(const float4*)(wsrc + ks * 32 + 4);
      short8 v;
      v[0] = (short)f2b(w0.x); v[1] = (short)f2b(w0.y);
      v[2] = (short)f2b(w0.z); v[3] = (short)f2b(w0.w);
      v[4] = (short)f2b(w1.x); v[5] = (short)f2b(w1.y);
      v[6] = (short)f2b(w1.z); v[7] = (short)f2b(w1.w);
      wfv[ks * 64 + lane] = v;
    }
  }

  #pragma unroll
  for (int grp = 0; grp < 2; ++grp) {
    int b0 = grp ? b0B : b0A;
    #pragma unroll
    for (int i = 0; i < 2; ++i) {
      int idx = tid + 64 * i;
      int b = b0 + (idx >> 3);
      int n = n0 + (idx & 7) * 2;
      const float* hp0 = h0 + (size_t)b * H_ + n;
      unsigned int dw = (unsigned int)f2b(hp0[0]) | ((unsigned int)f2b(hp0[1]) << 16);
      __hip_atomic_store((unsigned int*)(hbuf + (size_t)b * H_ + n), dw,
                         __ATOMIC_RELAXED, __HIP_MEMORY_SCOPE_AGENT);
    }
  }

  float hpA[4], hpB[4];
  #pragma unroll
  for (int r = 0; r < 4; ++r) {
    hpA[r] = h0[(size_t)(b0A + q * 4 + r) * H_ + n0 + col];
    hpB[r] = h0[(size_t)(b0B + q * 4 + r) * H_ + n0 + col];
  }

  WAIT_VM0();
  if (tid == 0) {
    __hip_atomic_store(&flags[(gA << 6) + member], 1, __ATOMIC_RELAXED, __HIP_MEMORY_SCOPE_AGENT);
    __hip_atomic_store(&flags[(gB << 6) + member], 1, __ATOMIC_RELAXED, __HIP_MEMORY_SCOPE_AGENT);
  }

  for (int t = 1; t <= T_; ++t) {
    float zvA[4], avA[4], zvB[4], avB[4];
    {
      const size_t baseA = (size_t)(t - 1) * BH + (size_t)(b0A + q * 4) * H_ + n0 + col;
      const size_t baseB = (size_t)(t - 1) * BH + (size_t)(b0B + q * 4) * H_ + n0 + col;
      #pragma unroll
      for (int r = 0; r < 4; ++r) {
        zvA[r] = b2f(z[baseA + (size_t)r * H_]);
        avA[r] = b2f(a[baseA + (size_t)r * H_]);
        zvB[r] = b2f(z[baseB + (size_t)r * H_]);
        avB[r] = b2f(a[baseB + (size_t)r * H_]);
      }
    }
    scan_step(t, gA, b0A, n0, lane, q, col, wfv, hbuf, hfinal, flags, zvA, avA, hpA);
    scan_step(t, gB, b0B, n0, lane, q, col, wfv, hbuf, hfinal, flags, zvB, avB, hpB);
  }
}

// ---------- launcher ----------
extern "C" void kernel_launch(void* const* d_in, const int* in_sizes, int n_in,
                              void* d_out, int out_size, void* d_ws, size_t ws_size,
                              hipStream_t stream) {
  const float* inputs = (const float*)d_in[0];
  const float* h0     = (const float*)d_in[1];
  const float* W_in   = (const float*)d_in[2];
  const float* b_in   = (const float*)d_in[3];
  const float* W_gate = (const float*)d_in[4];
  const float* b_gate = (const float*)d_in[5];
  const float* W_out  = (const float*)d_in[6];
  const float* b_out  = (const float*)d_in[7];

  char* ws = (char*)d_ws;
  ushort* Winbf  = (ushort*)(ws + 0);                        // 1 MB
  ushort* Wgzbf  = (ushort*)(ws + (1u << 20));               // 2 MB
  ushort* Woutbf = (ushort*)(ws + 3 * (1u << 20));           // 1 MB
  ushort* z_bf   = (ushort*)(ws + 4 * (1u << 20));           // 128 MB
  ushort* a_bf   = (ushort*)(ws + (size_t)4 * (1u << 20) + (size_t)134217728);
  ushort* hbuf   = (ushort*)(ws + (size_t)4 * (1u << 20) + (size_t)2 * 134217728);
  int*    flags  = (int*)   (ws + (size_t)4 * (1u << 20) + (size_t)2 * 134217728 + (size_t)134348800);

  // Abf (bf16 inputs, [(t*64+b)][I], 64 MB) aliases a_bf: only live until G1
  // completes; G2 (which writes a_bf) runs strictly after G1.
  ushort* Abf = a_bf;

  hipMemsetAsync(flags, 0, 4 * 64 * sizeof(int), stream);

  // casts
  cast4_kernel<<<dim3((H_ * I_ / 4 + 255) / 256), dim3(256), 0, stream>>>(W_in, Winbf, H_ * I_ / 4);
  cast4_kernel<<<dim3((O_ * H_ / 4 + 255) / 256), dim3(256), 0, stream>>>(W_out, Woutbf, O_ * H_ / 4);
  cast_gate_kernel<<<dim3(H_ * H_ / 4 / 256), dim3(256), 0, stream>>>(W_gate, Wgzbf);
  cast_inputs_kernel<<<dim3(B_ * T_ * I_ / 4 / 256), dim3(256), 0, stream>>>(inputs, Abf);

  // G1: z[(t*64+b), h] = Abf @ W_in^T + b_in
  gemm_bt_tiled<<<dim3(H_ / 128, (B_ * T_) / 128), dim3(256), 0, stream>>>(
      Abf, Winbf, b_in, (void*)z_bf, B_ * T_, H_, I_, 0);

  // G2: a = z @ Wg_z^T + b_gate
  gemm_bt_tiled<<<dim3(H_ / 128, (B_ * T_) / 128), dim3(256), 0, stream>>>(
      z_bf, Wgzbf, b_gate, (void*)a_bf, B_ * T_, H_, H_, 0);

  // scan (cooperative: 128 co-resident WGs required)
  {
    float* hfinal = (float*)d_out + (size_t)B_ * T_ * O_;
    const ushort* zc = z_bf; const ushort* ac = a_bf;
    ushort* hb = hbuf; const float* wg = W_gate; const float* h0c = h0;
    int* flg = flags;
    void* sargs[7] = { (void*)&zc, (void*)&ac, (void*)&hb, (void*)&wg,
                       (void*)&h0c, (void*)&hfinal, (void*)&flg };
    hipLaunchCooperativeKernel((const void*)scan_kernel, dim3(128), dim3(64), sargs, 0, stream);
  }

  // G3: outs[b,t,o] = hs[(t*64+b),:] @ W_out^T + b_out
  gemm_bt_tiled<<<dim3(O_ / 128, (B_ * T_) / 128), dim3(256), 0, stream>>>(
      hbuf + BH, Woutbf, b_out, d_out, B_ * T_, O_, H_, 1);
}